// Round 1
// baseline (86.590 us; speedup 1.0000x reference)
//
#include <hip/hip_runtime.h>
#include <hip/hip_bf16.h>
#include <stdint.h>

// PairRelationEncoder: out[b,e,s] = b2[s] + sum_r W2[s,r]*relu(b1[r] + sum_f W1[r,f]*pair[b,e,f])
// pair = [zi, zj, zi-zj, zi*zj]  -- folded to [zi, zj, zi*zj] with Wzi=W1a+W1c, Wzj=W1b-W1c.
// B=4 N=4096 D=64 E=131072 R=64. Out f32 (4,131072,64).

typedef __attribute__((ext_vector_type(8))) __bf16 bf16x8;
typedef __attribute__((ext_vector_type(4))) float  f32x4;

#define E_TOT 131072
#define N_TOK 4096
#define D_DIM 64
#define ROWS_PER_BLOCK 512
#define NSUB 8   // 8 subtiles x 64 rows

__device__ __forceinline__ f32x4 mfma16(bf16x8 a, bf16x8 b, f32x4 c) {
    return __builtin_amdgcn_mfma_f32_16x16x32_bf16(a, b, c, 0, 0, 0);
}

__device__ __forceinline__ bf16x8 pk8(float4 a, float4 b) {
    bf16x8 r;
    r[0] = (__bf16)a.x; r[1] = (__bf16)a.y; r[2] = (__bf16)a.z; r[3] = (__bf16)a.w;
    r[4] = (__bf16)b.x; r[5] = (__bf16)b.y; r[6] = (__bf16)b.z; r[7] = (__bf16)b.w;
    return r;
}
__device__ __forceinline__ float4 f4add(float4 a, float4 b){ return make_float4(a.x+b.x, a.y+b.y, a.z+b.z, a.w+b.w); }
__device__ __forceinline__ float4 f4sub(float4 a, float4 b){ return make_float4(a.x-b.x, a.y-b.y, a.z-b.z, a.w-b.w); }
__device__ __forceinline__ float4 f4mul(float4 a, float4 b){ return make_float4(a.x*b.x, a.y*b.y, a.z*b.z, a.w*b.w); }

__global__ __launch_bounds__(256, 2) void PairRelationEncoder_62775241998442_kernel(
    const float* __restrict__ z, const int* __restrict__ pairs,
    const float* __restrict__ W1, const float* __restrict__ b1,
    const float* __restrict__ W2, const float* __restrict__ b2,
    float* __restrict__ out)
{
    const int tid  = threadIdx.x;
    const int wave = tid >> 6;
    const int lane = tid & 63;
    const int x = lane & 15;   // MFMA: A-row / B-col / C-col
    const int g = lane >> 4;   // k-group (8 k's each)

    const int m0 = blockIdx.x * ROWS_PER_BLOCK;
    const int b  = m0 >> 17;            // / E_TOT
    const int e0 = m0 & (E_TOT - 1);
    const float* zb = z + ((size_t)b * N_TOK * D_DIM);

    // ---- layer-1 B-fragments in registers: B[k][col=r] = Wcomb[r][k], k = kk*32 + g*8 + j ----
    bf16x8 wzi[4][2], wzj[4][2], wpr[4][2];
#pragma unroll
    for (int ct = 0; ct < 4; ++ct) {
        const float* wr = W1 + (size_t)(ct * 16 + x) * 256;
#pragma unroll
        for (int h = 0; h < 2; ++h) {
            const int off = h * 32 + g * 8;
            float4 zi0 = *(const float4*)(wr + off);
            float4 zi1 = *(const float4*)(wr + off + 4);
            float4 zj0 = *(const float4*)(wr + 64 + off);
            float4 zj1 = *(const float4*)(wr + 64 + off + 4);
            float4 df0 = *(const float4*)(wr + 128 + off);
            float4 df1 = *(const float4*)(wr + 128 + off + 4);
            float4 pr0 = *(const float4*)(wr + 192 + off);
            float4 pr1 = *(const float4*)(wr + 192 + off + 4);
            wzi[ct][h] = pk8(f4add(zi0, df0), f4add(zi1, df1));
            wzj[ct][h] = pk8(f4sub(zj0, df0), f4sub(zj1, df1));
            wpr[ct][h] = pk8(pr0, pr1);
        }
    }

    // ---- layer-2 B-fragments: B[k=r][col=s] = W2[s][r] ----
    bf16x8 w2f[4][2];
#pragma unroll
    for (int ct = 0; ct < 4; ++ct) {
        const float* wr = W2 + (size_t)(ct * 16 + x) * 64;
#pragma unroll
        for (int kk = 0; kk < 2; ++kk) {
            const float* p = wr + kk * 32 + g * 8;
            w2f[ct][kk] = pk8(*(const float4*)p, *(const float4*)(p + 4));
        }
    }

    float b1v[4], b2v[4];
#pragma unroll
    for (int ct = 0; ct < 4; ++ct) { b1v[ct] = b1[ct*16 + x]; b2v[ct] = b2[ct*16 + x]; }

    // wave-private 16x64 bf16 h1 buffer, XOR-swizzled rows (kills stride-128B bank conflict)
    __shared__ __bf16 h1s[4][1024];
    __bf16* h1w = h1s[wave];

    for (int st = 0; st < NSUB; ++st) {
        const int e = e0 + st * 64 + wave * 16 + x;
        const int2 ij = *(const int2*)(pairs + 2 * (size_t)e);
        const float4* zi4 = (const float4*)(zb + (size_t)ij.x * D_DIM);
        const float4* zj4 = (const float4*)(zb + (size_t)ij.y * D_DIM);

        // lane covers d = g*8..g*8+7 (h=0) and d = 32+g*8..+7 (h=1) of its row x
        float4 ia0 = zi4[2*g],     ia1 = zi4[2*g + 1];
        float4 ib0 = zi4[8 + 2*g], ib1 = zi4[8 + 2*g + 1];
        float4 ja0 = zj4[2*g],     ja1 = zj4[2*g + 1];
        float4 jb0 = zj4[8 + 2*g], jb1 = zj4[8 + 2*g + 1];

        bf16x8 A[6];
        A[0] = pk8(ia0, ia1);  A[1] = pk8(ib0, ib1);
        A[2] = pk8(ja0, ja1);  A[3] = pk8(jb0, jb1);
        A[4] = pk8(f4mul(ia0, ja0), f4mul(ia1, ja1));
        A[5] = pk8(f4mul(ib0, jb0), f4mul(ib1, jb1));

        f32x4 acc[4];
#pragma unroll
        for (int ct = 0; ct < 4; ++ct) { acc[ct][0]=0.f; acc[ct][1]=0.f; acc[ct][2]=0.f; acc[ct][3]=0.f; }

#pragma unroll
        for (int h = 0; h < 2; ++h)
#pragma unroll
            for (int ct = 0; ct < 4; ++ct) {
                acc[ct] = mfma16(A[h],     wzi[ct][h], acc[ct]);
                acc[ct] = mfma16(A[2 + h], wzj[ct][h], acc[ct]);
                acc[ct] = mfma16(A[4 + h], wpr[ct][h], acc[ct]);
            }

        // layer-1 epilogue: bias, relu, bf16 -> LDS (C layout: row=g*4+r, col=ct*16+x)
#pragma unroll
        for (int ct = 0; ct < 4; ++ct)
#pragma unroll
            for (int r = 0; r < 4; ++r) {
                const int row = g * 4 + r;
                float v = acc[ct][r] + b1v[ct];
                v = fmaxf(v, 0.f);
                const int eo = (row * 64 + ct * 16 + x) ^ ((row & 7) << 3);
                h1w[eo] = (__bf16)v;
            }

        f32x4 o[4];
#pragma unroll
        for (int ct = 0; ct < 4; ++ct) { o[ct][0]=0.f; o[ct][1]=0.f; o[ct][2]=0.f; o[ct][3]=0.f; }

        // layer-2: A-frag row = x, k = kk*32 + g*8 + j  (wave-private LDS, no barrier needed)
#pragma unroll
        for (int kk = 0; kk < 2; ++kk) {
            const int byteoff = (x * 128 + kk * 64 + g * 16) ^ ((x & 7) << 4);
            const bf16x8 a2 = *(const bf16x8*)((const char*)h1w + byteoff);
#pragma unroll
            for (int ct = 0; ct < 4; ++ct)
                o[ct] = mfma16(a2, w2f[ct][kk], o[ct]);
        }

        float* orow = out + ((size_t)(m0 + st * 64 + wave * 16)) * 64;
#pragma unroll
        for (int ct = 0; ct < 4; ++ct)
#pragma unroll
            for (int r = 0; r < 4; ++r) {
                const int row = g * 4 + r;
                orow[(size_t)row * 64 + ct * 16 + x] = o[ct][r] + b2v[ct];
            }
    }
}

extern "C" void kernel_launch(void* const* d_in, const int* in_sizes, int n_in,
                              void* d_out, int out_size, void* d_ws, size_t ws_size,
                              hipStream_t stream) {
    const float* z     = (const float*)d_in[0];
    const int*   pairs = (const int*)  d_in[1];
    const float* W1    = (const float*)d_in[2];
    const float* b1    = (const float*)d_in[3];
    const float* W2    = (const float*)d_in[4];
    const float* b2    = (const float*)d_in[5];
    float* out = (float*)d_out;

    const int total_rows = 4 * E_TOT;                 // 524288
    dim3 grid(total_rows / ROWS_PER_BLOCK);           // 1024
    PairRelationEncoder_62775241998442_kernel<<<grid, 256, 0, stream>>>(
        z, pairs, W1, b1, W2, b2, out);
}

// Round 2
// 68.018 us; speedup vs baseline: 1.2730x; 1.2730x over previous
//
#include <hip/hip_runtime.h>
#include <hip/hip_bf16.h>
#include <stdint.h>

// PairRelationEncoder: out[b,e,s] = b2[s] + sum_r W2[s,r]*relu(b1[r] + sum_f W1[r,f]*pair[b,e,f])
// pair = [zi, zj, zi-zj, zi*zj]  folded to [zi, zj, zi*zj]: Wzi=W1a+W1c, Wzj=W1b-W1c, Wpr=W1d.
// B=4 N=4096 D=64 E=131072 R=64. Out f32 (4,131072,64).
//
// R1: weights in VGPRs -> ~230 true regs -> 2 waves/SIMD, latency-naked (90us, all pipes idle).
// R2: weights staged ONCE per block into LDS as packed bf16 frags (shared by 4 waves, frees
//     ~128 VGPRs), pairs hoisted, z-gather pipelined depth-1, grid 2048.

typedef __attribute__((ext_vector_type(8))) __bf16 bf16x8;
typedef __attribute__((ext_vector_type(4))) float  f32x4;

#define E_TOT 131072
#define N_TOK 4096
#define ROWS_PER_BLOCK 256
#define NSUB 4   // 4 subtiles x 64 rows

__device__ __forceinline__ f32x4 mfma16(bf16x8 a, bf16x8 b, f32x4 c) {
    return __builtin_amdgcn_mfma_f32_16x16x32_bf16(a, b, c, 0, 0, 0);
}

__device__ __forceinline__ bf16x8 pk8(float4 a, float4 b) {
    bf16x8 r;
    r[0] = (__bf16)a.x; r[1] = (__bf16)a.y; r[2] = (__bf16)a.z; r[3] = (__bf16)a.w;
    r[4] = (__bf16)b.x; r[5] = (__bf16)b.y; r[6] = (__bf16)b.z; r[7] = (__bf16)b.w;
    return r;
}
__device__ __forceinline__ float4 f4add(float4 a, float4 b){ return make_float4(a.x+b.x, a.y+b.y, a.z+b.z, a.w+b.w); }
__device__ __forceinline__ float4 f4sub(float4 a, float4 b){ return make_float4(a.x-b.x, a.y-b.y, a.z-b.z, a.w-b.w); }
__device__ __forceinline__ float4 f4mul(float4 a, float4 b){ return make_float4(a.x*b.x, a.y*b.y, a.z*b.z, a.w*b.w); }

struct AF { bf16x8 a[6]; };  // pair-feature A-frags: zi(2), zj(2), zi*zj(2); all access unrolled

__device__ __forceinline__ AF mkA(const float* __restrict__ zb, int2 ij, int g) {
    const float4* zi4 = (const float4*)(zb + (size_t)ij.x * 64);
    const float4* zj4 = (const float4*)(zb + (size_t)ij.y * 64);
    float4 ia0 = zi4[2*g],     ia1 = zi4[2*g + 1];
    float4 ib0 = zi4[8 + 2*g], ib1 = zi4[8 + 2*g + 1];
    float4 ja0 = zj4[2*g],     ja1 = zj4[2*g + 1];
    float4 jb0 = zj4[8 + 2*g], jb1 = zj4[8 + 2*g + 1];
    AF f;
    f.a[0] = pk8(ia0, ia1);  f.a[1] = pk8(ib0, ib1);
    f.a[2] = pk8(ja0, ja1);  f.a[3] = pk8(jb0, jb1);
    f.a[4] = pk8(f4mul(ia0, ja0), f4mul(ia1, ja1));
    f.a[5] = pk8(f4mul(ib0, jb0), f4mul(ib1, jb1));
    return f;
}

__global__ __launch_bounds__(256, 3) void PairRelationEncoder_62775241998442_kernel(
    const float* __restrict__ z, const int* __restrict__ pairs,
    const float* __restrict__ W1, const float* __restrict__ b1,
    const float* __restrict__ W2, const float* __restrict__ b2,
    float* __restrict__ out)
{
    const int tid  = threadIdx.x;
    const int wave = tid >> 6;
    const int lane = tid & 63;
    const int x = lane & 15;   // MFMA: A-row / B-col / C-col
    const int g = lane >> 4;   // k-group

    const int m0 = blockIdx.x * ROWS_PER_BLOCK;
    const int b  = m0 >> 17;
    const int e0 = m0 & (E_TOT - 1);
    const float* zb = z + ((size_t)b * N_TOK * 64);

    // hoisted pairs (issue first; overlaps weight staging)
    int2 ijv[NSUB];
#pragma unroll
    for (int st = 0; st < NSUB; ++st)
        ijv[st] = *(const int2*)(pairs + 2 * (size_t)(e0 + st * 64 + wave * 16 + x));

    // LDS: folded-W1 bf16 [col=r(64)][k(192)] swizzled, W2 bf16 [col=s(64)][k=r(64)] swizzled,
    // per-wave h1 transpose buffer. 24K + 8K + 8K = 40960 B.
    __shared__ __bf16 w1s[64 * 192];
    __shared__ __bf16 w2s[64 * 64];
    __shared__ __bf16 h1s[4][1024];
    __bf16* h1w = h1s[wave];

    // ---- one-time weight staging: wave 0..2 -> W1 sections zi/zj/pr, wave 3 -> W2 ----
    {
        const int scol = tid & 63;
        const int ssec = tid >> 6;           // wave-uniform
        const int cswz = (scol & 7) << 4;
        if (ssec < 3) {
            const float* wr = W1 + (size_t)scol * 256;
            char* dst = (char*)w1s + scol * 384;
#pragma unroll
            for (int c8 = 0; c8 < 8; ++c8) {
                float4 p0, p1;
                if (ssec == 0) {        // zi: W1a + W1c
                    float4 a0 = *(const float4*)(wr + c8*8);
                    float4 a1 = *(const float4*)(wr + c8*8 + 4);
                    float4 c0 = *(const float4*)(wr + 128 + c8*8);
                    float4 c1 = *(const float4*)(wr + 128 + c8*8 + 4);
                    p0 = f4add(a0, c0); p1 = f4add(a1, c1);
                } else if (ssec == 1) { // zj: W1b - W1c
                    float4 a0 = *(const float4*)(wr + 64 + c8*8);
                    float4 a1 = *(const float4*)(wr + 64 + c8*8 + 4);
                    float4 c0 = *(const float4*)(wr + 128 + c8*8);
                    float4 c1 = *(const float4*)(wr + 128 + c8*8 + 4);
                    p0 = f4sub(a0, c0); p1 = f4sub(a1, c1);
                } else {                // pr: W1d
                    p0 = *(const float4*)(wr + 192 + c8*8);
                    p1 = *(const float4*)(wr + 192 + c8*8 + 4);
                }
                const int kbyte = ssec * 128 + c8 * 16;
                *(bf16x8*)(dst + (kbyte ^ cswz)) = pk8(p0, p1);
            }
        } else {                        // W2 row s -> [col=s][k=r]
            const float* wr = W2 + (size_t)scol * 64;
            char* dst = (char*)w2s + scol * 128;
#pragma unroll
            for (int c8 = 0; c8 < 8; ++c8) {
                float4 p0 = *(const float4*)(wr + c8*8);
                float4 p1 = *(const float4*)(wr + c8*8 + 4);
                *(bf16x8*)(dst + ((c8 * 16) ^ cswz)) = pk8(p0, p1);
            }
        }
    }

    float b1v[4], b2v[4];
#pragma unroll
    for (int ct = 0; ct < 4; ++ct) { b1v[ct] = b1[ct*16 + x]; b2v[ct] = b2[ct*16 + x]; }

    __syncthreads();

    // ---- pipelined main loop ----
    AF cur = mkA(zb, ijv[0], g);

#pragma unroll
    for (int st = 0; st < NSUB; ++st) {
        AF nxt;
        if (st + 1 < NSUB) { nxt = mkA(zb, ijv[st + 1 < NSUB ? st + 1 : 0], g); }
        else               { nxt = cur; }

        // ---- layer 1: 24 MFMA, B-frags streamed from LDS ----
        f32x4 acc[4];
#pragma unroll
        for (int ct = 0; ct < 4; ++ct) { acc[ct][0]=0.f; acc[ct][1]=0.f; acc[ct][2]=0.f; acc[ct][3]=0.f; }

#pragma unroll
        for (int h = 0; h < 2; ++h) {
#pragma unroll
            for (int ct = 0; ct < 4; ++ct) {
                const int colr = ct * 16 + x;
                const int cswz = (colr & 7) << 4;
                const char* wb = (const char*)w1s + colr * 384;
                const int kb = h * 64 + g * 16;
                bf16x8 bzi = *(const bf16x8*)(wb + ((kb      ) ^ cswz));
                bf16x8 bzj = *(const bf16x8*)(wb + ((kb + 128) ^ cswz));
                bf16x8 bpr = *(const bf16x8*)(wb + ((kb + 256) ^ cswz));
                acc[ct] = mfma16(cur.a[h],     bzi, acc[ct]);
                acc[ct] = mfma16(cur.a[2 + h], bzj, acc[ct]);
                acc[ct] = mfma16(cur.a[4 + h], bpr, acc[ct]);
            }
        }

        // ---- layer-1 epilogue: bias+relu+bf16 -> wave-private LDS (transpose) ----
#pragma unroll
        for (int ct = 0; ct < 4; ++ct)
#pragma unroll
            for (int r = 0; r < 4; ++r) {
                const int row = g * 4 + r;
                float v = fmaxf(acc[ct][r] + b1v[ct], 0.f);
                const int eo = (row * 64 + ct * 16 + x) ^ ((row & 7) << 3);
                h1w[eo] = (__bf16)v;
            }

        // ---- layer 2: 8 MFMA ----
        f32x4 o[4];
#pragma unroll
        for (int ct = 0; ct < 4; ++ct) { o[ct][0]=0.f; o[ct][1]=0.f; o[ct][2]=0.f; o[ct][3]=0.f; }

#pragma unroll
        for (int kk = 0; kk < 2; ++kk) {
            const int aoff = (x * 128 + kk * 64 + g * 16) ^ ((x & 7) << 4);
            const bf16x8 a2 = *(const bf16x8*)((const char*)h1w + aoff);
#pragma unroll
            for (int ct = 0; ct < 4; ++ct) {
                const int cols = ct * 16 + x;
                const bf16x8 b2f = *(const bf16x8*)((const char*)w2s + cols * 128
                                                    + ((kk * 64 + g * 16) ^ ((cols & 7) << 4)));
                o[ct] = mfma16(a2, b2f, o[ct]);
            }
        }

        // ---- store ----
        float* orow = out + ((size_t)(m0 + st * 64 + wave * 16)) * 64;
#pragma unroll
        for (int ct = 0; ct < 4; ++ct)
#pragma unroll
            for (int r = 0; r < 4; ++r) {
                const int row = g * 4 + r;
                orow[(size_t)row * 64 + ct * 16 + x] = o[ct][r] + b2v[ct];
            }

        cur = nxt;
    }
}

extern "C" void kernel_launch(void* const* d_in, const int* in_sizes, int n_in,
                              void* d_out, int out_size, void* d_ws, size_t ws_size,
                              hipStream_t stream) {
    const float* z     = (const float*)d_in[0];
    const int*   pairs = (const int*)  d_in[1];
    const float* W1    = (const float*)d_in[2];
    const float* b1    = (const float*)d_in[3];
    const float* W2    = (const float*)d_in[4];
    const float* b2    = (const float*)d_in[5];
    float* out = (float*)d_out;

    const int total_rows = 4 * E_TOT;                 // 524288
    dim3 grid(total_rows / ROWS_PER_BLOCK);           // 2048
    PairRelationEncoder_62775241998442_kernel<<<grid, 256, 0, stream>>>(
        z, pairs, W1, b1, W2, b2, out);
}

// Round 3
// 62.980 us; speedup vs baseline: 1.3749x; 1.0800x over previous
//
#include <hip/hip_runtime.h>
#include <hip/hip_bf16.h>
#include <stdint.h>

// PairRelationEncoder: out[b,e,s] = b2[s] + sum_r W2[s,r]*relu(b1[r] + sum_f W1[r,f]*pair[b,e,f])
// pair = [zi, zj, zi-zj, zi*zj] folded to [zi, zj, zi*zj]: Wzi=W1a+W1c, Wzj=W1b-W1c, Wpr=W1d.
// B=4 N=4096 D=64 E=131072 R=64. Out f32 (4,131072,64).
//
// R3: TRANSPOSED dataflow (h1^T = W1f*pair^T, out^T = W2*h1^T). Frag layouts are A/B-symmetric
// so weight reads unchanged, but hand-off = 4x ds_write_b64 (was 16x b16), stores = 4x dwordx4
// (was 16x dword), bias = accumulator init from LDS broadcast reads. 512-thr blocks, 4 waves/SIMD.

typedef __attribute__((ext_vector_type(8))) __bf16 bf16x8;
typedef __attribute__((ext_vector_type(4))) __bf16 bf16x4;
typedef __attribute__((ext_vector_type(4))) float  f32x4;

#define E_TOT 131072
#define N_TOK 4096
#define ROWS_PER_BLOCK 512
#define NSUB 4   // per wave: 4 subtiles x 16 pairs (8 waves -> 512 rows/block)

__device__ __forceinline__ f32x4 mfma16(bf16x8 a, bf16x8 b, f32x4 c) {
    return __builtin_amdgcn_mfma_f32_16x16x32_bf16(a, b, c, 0, 0, 0);
}

__device__ __forceinline__ bf16x8 pk8(float4 a, float4 b) {
    bf16x8 r;
    r[0] = (__bf16)a.x; r[1] = (__bf16)a.y; r[2] = (__bf16)a.z; r[3] = (__bf16)a.w;
    r[4] = (__bf16)b.x; r[5] = (__bf16)b.y; r[6] = (__bf16)b.z; r[7] = (__bf16)b.w;
    return r;
}
__device__ __forceinline__ float4 f4add(float4 a, float4 b){ return make_float4(a.x+b.x, a.y+b.y, a.z+b.z, a.w+b.w); }
__device__ __forceinline__ float4 f4sub(float4 a, float4 b){ return make_float4(a.x-b.x, a.y-b.y, a.z-b.z, a.w-b.w); }
__device__ __forceinline__ float4 f4mul(float4 a, float4 b){ return make_float4(a.x*b.x, a.y*b.y, a.z*b.z, a.w*b.w); }

struct AF { bf16x8 a[6]; };  // pair-feature B-frags: zi(h0,h1), zj(h0,h1), zi*zj(h0,h1)

__device__ __forceinline__ AF mkA(const float* __restrict__ zb, int2 ij, int g) {
    const float4* zi4 = (const float4*)(zb + (size_t)ij.x * 64);
    const float4* zj4 = (const float4*)(zb + (size_t)ij.y * 64);
    float4 ia0 = zi4[2*g],     ia1 = zi4[2*g + 1];
    float4 ib0 = zi4[8 + 2*g], ib1 = zi4[8 + 2*g + 1];
    float4 ja0 = zj4[2*g],     ja1 = zj4[2*g + 1];
    float4 jb0 = zj4[8 + 2*g], jb1 = zj4[8 + 2*g + 1];
    AF f;
    f.a[0] = pk8(ia0, ia1);  f.a[1] = pk8(ib0, ib1);
    f.a[2] = pk8(ja0, ja1);  f.a[3] = pk8(jb0, jb1);
    f.a[4] = pk8(f4mul(ia0, ja0), f4mul(ia1, ja1));
    f.a[5] = pk8(f4mul(ib0, jb0), f4mul(ib1, jb1));
    return f;
}

__global__ __launch_bounds__(512, 4) void PairRelationEncoder_62775241998442_kernel(
    const float* __restrict__ z, const int* __restrict__ pairs,
    const float* __restrict__ W1, const float* __restrict__ b1,
    const float* __restrict__ W2, const float* __restrict__ b2,
    float* __restrict__ out)
{
    const int tid  = threadIdx.x;
    const int wave = tid >> 6;
    const int lane = tid & 63;
    const int x = lane & 15;   // e-index within subtile (B-col / C-col)
    const int g = lane >> 4;   // k-group

    // bijective XCD-chunked swizzle (1024 blocks, 8 XCDs): each XCD sees one batch's z slab
    const int bid = (int)(blockIdx.x & 7) * 128 + ((int)blockIdx.x >> 3);
    const int m0 = bid * ROWS_PER_BLOCK;
    const int b  = m0 >> 17;
    const int e0 = m0 & (E_TOT - 1);
    const float* zb = z + ((size_t)b * N_TOK * 64);

    // hoisted pairs
    int2 ijv[NSUB];
#pragma unroll
    for (int st = 0; st < NSUB; ++st)
        ijv[st] = *(const int2*)(pairs + 2 * (size_t)(e0 + (st * 8 + wave) * 16 + x));

    // LDS: W1f bf16 [r(64)][k(192)] swz, W2 bf16 [s(64)][r(64)] swz, per-wave h1^T [e(16)][r(64)],
    // bias f32. 24576 + 8192 + 16384 + 512 = 49664 B -> 2 blocks/CU.
    __shared__ __bf16 w1s[64 * 192];
    __shared__ __bf16 w2s[64 * 64];
    __shared__ __bf16 h1s[8][1024];
    __shared__ float  b1s[64];
    __shared__ float  b2s[64];
    __bf16* h1w = h1s[wave];

    // ---- one-time weight staging: 4 parts x 128 threads; each part 64 cols x 4 c8-iters ----
    {
        const int part = tid >> 7;            // 0:zi 1:zj 2:pr 3:W2
        const int scol = tid & 63;
        const int c8b  = ((tid >> 6) & 1) * 4;
        const int cswz = (scol & 7) << 4;
        if (part < 3) {
            const float* wr = W1 + (size_t)scol * 256;
            char* dst = (char*)w1s + scol * 384;
#pragma unroll
            for (int c = 0; c < 4; ++c) {
                const int c8 = c8b + c;
                float4 p0, p1;
                if (part == 0) {
                    float4 a0 = *(const float4*)(wr + c8*8);
                    float4 a1 = *(const float4*)(wr + c8*8 + 4);
                    float4 c0 = *(const float4*)(wr + 128 + c8*8);
                    float4 c1 = *(const float4*)(wr + 128 + c8*8 + 4);
                    p0 = f4add(a0, c0); p1 = f4add(a1, c1);
                } else if (part == 1) {
                    float4 a0 = *(const float4*)(wr + 64 + c8*8);
                    float4 a1 = *(const float4*)(wr + 64 + c8*8 + 4);
                    float4 c0 = *(const float4*)(wr + 128 + c8*8);
                    float4 c1 = *(const float4*)(wr + 128 + c8*8 + 4);
                    p0 = f4sub(a0, c0); p1 = f4sub(a1, c1);
                } else {
                    p0 = *(const float4*)(wr + 192 + c8*8);
                    p1 = *(const float4*)(wr + 192 + c8*8 + 4);
                }
                *(bf16x8*)(dst + ((part * 128 + c8 * 16) ^ cswz)) = pk8(p0, p1);
            }
        } else {
            const float* wr = W2 + (size_t)scol * 64;
            char* dst = (char*)w2s + scol * 128;
#pragma unroll
            for (int c = 0; c < 4; ++c) {
                const int c8 = c8b + c;
                float4 p0 = *(const float4*)(wr + c8*8);
                float4 p1 = *(const float4*)(wr + c8*8 + 4);
                *(bf16x8*)(dst + ((c8 * 16) ^ cswz)) = pk8(p0, p1);
            }
        }
        if (tid < 16)            ((float4*)b1s)[tid]      = ((const float4*)b1)[tid];
        else if (tid < 32)       ((float4*)b2s)[tid - 16] = ((const float4*)b2)[tid - 16];
    }

    // subtile-0 gather overlaps staging (independent of LDS)
    AF cur = mkA(zb, ijv[0], g);

    __syncthreads();

#pragma unroll
    for (int st = 0; st < NSUB; ++st) {
        AF nxt = (st + 1 < NSUB) ? mkA(zb, ijv[st + 1 < NSUB ? st + 1 : 0], g) : cur;

        // ---- layer 1 (transposed): acc[ct][q] = h1[r=ct*16+g*4+q][e=x], init = b1 ----
        f32x4 acc[4];
#pragma unroll
        for (int ct = 0; ct < 4; ++ct)
            acc[ct] = *(const f32x4*)(b1s + ct * 16 + g * 4);   // broadcast per quarter-wave

#pragma unroll
        for (int h = 0; h < 2; ++h) {
#pragma unroll
            for (int ct = 0; ct < 4; ++ct) {
                const int colr = ct * 16 + x;
                const int cswz = (colr & 7) << 4;
                const char* wb = (const char*)w1s + colr * 384;
                const int kb = h * 64 + g * 16;
                bf16x8 azi = *(const bf16x8*)(wb + ((kb      ) ^ cswz));
                bf16x8 azj = *(const bf16x8*)(wb + ((kb + 128) ^ cswz));
                bf16x8 apr = *(const bf16x8*)(wb + ((kb + 256) ^ cswz));
                acc[ct] = mfma16(azi, cur.a[h],     acc[ct]);
                acc[ct] = mfma16(azj, cur.a[2 + h], acc[ct]);
                acc[ct] = mfma16(apr, cur.a[4 + h], acc[ct]);
            }
        }

        // ---- epilogue: relu, pack 4xbf16, one ds_write_b64 per ct ----
#pragma unroll
        for (int ct = 0; ct < 4; ++ct) {
            bf16x4 p;
#pragma unroll
            for (int q = 0; q < 4; ++q)
                p[q] = (__bf16)fmaxf(acc[ct][q], 0.f);
            const int wo = (x * 128 + ct * 32 + g * 8) ^ ((x & 7) << 4);
            *(bf16x4*)((char*)h1w + wo) = p;
        }

        // ---- layer 2 (transposed): o[ct][q] = out[e=x][s=ct*16+g*4+q], init = b2 ----
        f32x4 o[4];
#pragma unroll
        for (int ct = 0; ct < 4; ++ct)
            o[ct] = *(const f32x4*)(b2s + ct * 16 + g * 4);

#pragma unroll
        for (int kk = 0; kk < 2; ++kk) {
            const int aoff = (x * 128 + kk * 64 + g * 16) ^ ((x & 7) << 4);
            const bf16x8 h1f = *(const bf16x8*)((const char*)h1w + aoff);
#pragma unroll
            for (int ct = 0; ct < 4; ++ct) {
                const int cols = ct * 16 + x;
                const bf16x8 w2f = *(const bf16x8*)((const char*)w2s + cols * 128
                                                    + ((kk * 64 + g * 16) ^ ((cols & 7) << 4)));
                o[ct] = mfma16(w2f, h1f, o[ct]);
            }
        }

        // ---- store: 4x global_store_dwordx4 ----
        float* orow = out + ((size_t)(m0 + (st * 8 + wave) * 16 + x)) * 64;
#pragma unroll
        for (int ct = 0; ct < 4; ++ct)
            *(f32x4*)(orow + ct * 16 + g * 4) = o[ct];

        cur = nxt;
    }
}

extern "C" void kernel_launch(void* const* d_in, const int* in_sizes, int n_in,
                              void* d_out, int out_size, void* d_ws, size_t ws_size,
                              hipStream_t stream) {
    const float* z     = (const float*)d_in[0];
    const int*   pairs = (const int*)  d_in[1];
    const float* W1    = (const float*)d_in[2];
    const float* b1    = (const float*)d_in[3];
    const float* W2    = (const float*)d_in[4];
    const float* b2    = (const float*)d_in[5];
    float* out = (float*)d_out;

    const int total_rows = 4 * E_TOT;                 // 524288
    dim3 grid(total_rows / ROWS_PER_BLOCK);           // 1024
    PairRelationEncoder_62775241998442_kernel<<<grid, 512, 0, stream>>>(
        z, pairs, W1, b1, W2, b2, out);
}

// Round 4
// 58.944 us; speedup vs baseline: 1.4690x; 1.0685x over previous
//
#include <hip/hip_runtime.h>
#include <hip/hip_bf16.h>
#include <stdint.h>

// PairRelationEncoder: out[b,e,s] = b2[s] + sum_r W2[s,r]*relu(b1[r] + sum_f W1[r,f]*pair[b,e,f])
// pair = [zi, zj, zi-zj, zi*zj] folded to [zi, zj, zi*zj]: Wzi=W1a+W1c, Wzj=W1b-W1c, Wpr=W1d.
// B=4 N=4096 D=64 E=131072 R=64. Out f32 (4,131072,64).
//
// R4: transposed dataflow kept; manual AF double-buffer REMOVED to cut peak VGPR below 128
// so 2 blocks/CU (16 waves, 4/SIMD) actually become resident. Compiler pipelines the
// unrolled loop within its real register budget. s_setprio around MFMA clusters.

typedef __attribute__((ext_vector_type(8))) __bf16 bf16x8;
typedef __attribute__((ext_vector_type(4))) __bf16 bf16x4;
typedef __attribute__((ext_vector_type(4))) float  f32x4;

#define E_TOT 131072
#define N_TOK 4096
#define ROWS_PER_BLOCK 512
#define NSUB 4   // per wave: 4 subtiles x 16 pairs (8 waves -> 512 rows/block)

__device__ __forceinline__ f32x4 mfma16(bf16x8 a, bf16x8 b, f32x4 c) {
    return __builtin_amdgcn_mfma_f32_16x16x32_bf16(a, b, c, 0, 0, 0);
}

__device__ __forceinline__ bf16x8 pk8(float4 a, float4 b) {
    bf16x8 r;
    r[0] = (__bf16)a.x; r[1] = (__bf16)a.y; r[2] = (__bf16)a.z; r[3] = (__bf16)a.w;
    r[4] = (__bf16)b.x; r[5] = (__bf16)b.y; r[6] = (__bf16)b.z; r[7] = (__bf16)b.w;
    return r;
}
__device__ __forceinline__ float4 f4add(float4 a, float4 b){ return make_float4(a.x+b.x, a.y+b.y, a.z+b.z, a.w+b.w); }
__device__ __forceinline__ float4 f4sub(float4 a, float4 b){ return make_float4(a.x-b.x, a.y-b.y, a.z-b.z, a.w-b.w); }
__device__ __forceinline__ float4 f4mul(float4 a, float4 b){ return make_float4(a.x*b.x, a.y*b.y, a.z*b.z, a.w*b.w); }

__global__ __launch_bounds__(512, 4) void PairRelationEncoder_62775241998442_kernel(
    const float* __restrict__ z, const int* __restrict__ pairs,
    const float* __restrict__ W1, const float* __restrict__ b1,
    const float* __restrict__ W2, const float* __restrict__ b2,
    float* __restrict__ out)
{
    const int tid  = threadIdx.x;
    const int wave = tid >> 6;
    const int lane = tid & 63;
    const int x = lane & 15;   // e-index within subtile (B-col / C-col)
    const int g = lane >> 4;   // k-group

    // bijective XCD-chunked swizzle (1024 blocks, 8 XCDs): each XCD sees one batch's z slab
    const int bid = (int)(blockIdx.x & 7) * 128 + ((int)blockIdx.x >> 3);
    const int m0 = bid * ROWS_PER_BLOCK;
    const int b  = m0 >> 17;
    const int e0 = m0 & (E_TOT - 1);
    const float* zb = z + ((size_t)b * N_TOK * 64);

    // hoisted pairs
    int2 ijv[NSUB];
#pragma unroll
    for (int st = 0; st < NSUB; ++st)
        ijv[st] = *(const int2*)(pairs + 2 * (size_t)(e0 + (st * 8 + wave) * 16 + x));

    // LDS: W1f bf16 [r(64)][k(192)] swz, W2 bf16 [s(64)][r(64)] swz, per-wave h1^T, biases f32.
    // 24576 + 8192 + 16384 + 512 = 49664 B -> 2 blocks/CU.
    __shared__ __bf16 w1s[64 * 192];
    __shared__ __bf16 w2s[64 * 64];
    __shared__ __bf16 h1s[8][1024];
    __shared__ float  b1s[64];
    __shared__ float  b2s[64];
    __bf16* h1w = h1s[wave];

    // ---- one-time weight staging: 4 parts x 128 threads; each part 64 cols x 4 c8-iters ----
    {
        const int part = tid >> 7;            // 0:zi 1:zj 2:pr 3:W2
        const int scol = tid & 63;
        const int c8b  = ((tid >> 6) & 1) * 4;
        const int cswz = (scol & 7) << 4;
        if (part < 3) {
            const float* wr = W1 + (size_t)scol * 256;
            char* dst = (char*)w1s + scol * 384;
#pragma unroll
            for (int c = 0; c < 4; ++c) {
                const int c8 = c8b + c;
                float4 p0, p1;
                if (part == 0) {
                    float4 a0 = *(const float4*)(wr + c8*8);
                    float4 a1 = *(const float4*)(wr + c8*8 + 4);
                    float4 c0 = *(const float4*)(wr + 128 + c8*8);
                    float4 c1 = *(const float4*)(wr + 128 + c8*8 + 4);
                    p0 = f4add(a0, c0); p1 = f4add(a1, c1);
                } else if (part == 1) {
                    float4 a0 = *(const float4*)(wr + 64 + c8*8);
                    float4 a1 = *(const float4*)(wr + 64 + c8*8 + 4);
                    float4 c0 = *(const float4*)(wr + 128 + c8*8);
                    float4 c1 = *(const float4*)(wr + 128 + c8*8 + 4);
                    p0 = f4sub(a0, c0); p1 = f4sub(a1, c1);
                } else {
                    p0 = *(const float4*)(wr + 192 + c8*8);
                    p1 = *(const float4*)(wr + 192 + c8*8 + 4);
                }
                *(bf16x8*)(dst + ((part * 128 + c8 * 16) ^ cswz)) = pk8(p0, p1);
            }
        } else {
            const float* wr = W2 + (size_t)scol * 64;
            char* dst = (char*)w2s + scol * 128;
#pragma unroll
            for (int c = 0; c < 4; ++c) {
                const int c8 = c8b + c;
                float4 p0 = *(const float4*)(wr + c8*8);
                float4 p1 = *(const float4*)(wr + c8*8 + 4);
                *(bf16x8*)(dst + ((c8 * 16) ^ cswz)) = pk8(p0, p1);
            }
        }
        if (tid < 16)            ((float4*)b1s)[tid]      = ((const float4*)b1)[tid];
        else if (tid < 32)       ((float4*)b2s)[tid - 16] = ((const float4*)b2)[tid - 16];
    }

    __syncthreads();

#pragma unroll
    for (int st = 0; st < NSUB; ++st) {
        // ---- gather + pack pair-feature B-frags (compiler pipelines across st) ----
        const float4* zi4 = (const float4*)(zb + (size_t)ijv[st].x * 64);
        const float4* zj4 = (const float4*)(zb + (size_t)ijv[st].y * 64);
        float4 ia0 = zi4[2*g],     ia1 = zi4[2*g + 1];
        float4 ib0 = zi4[8 + 2*g], ib1 = zi4[8 + 2*g + 1];
        float4 ja0 = zj4[2*g],     ja1 = zj4[2*g + 1];
        float4 jb0 = zj4[8 + 2*g], jb1 = zj4[8 + 2*g + 1];
        bf16x8 a0 = pk8(ia0, ia1);
        bf16x8 a1 = pk8(ib0, ib1);
        bf16x8 a2 = pk8(ja0, ja1);
        bf16x8 a3 = pk8(jb0, jb1);
        bf16x8 a4 = pk8(f4mul(ia0, ja0), f4mul(ia1, ja1));
        bf16x8 a5 = pk8(f4mul(ib0, jb0), f4mul(ib1, jb1));

        // ---- layer 1 (transposed): acc[ct][q] = h1[r=ct*16+g*4+q][e=x], init = b1 ----
        f32x4 acc[4];
#pragma unroll
        for (int ct = 0; ct < 4; ++ct)
            acc[ct] = *(const f32x4*)(b1s + ct * 16 + g * 4);

        __builtin_amdgcn_s_setprio(1);
#pragma unroll
        for (int h = 0; h < 2; ++h) {
#pragma unroll
            for (int ct = 0; ct < 4; ++ct) {
                const int colr = ct * 16 + x;
                const int cswz = (colr & 7) << 4;
                const char* wb = (const char*)w1s + colr * 384;
                const int kb = h * 64 + g * 16;
                bf16x8 azi = *(const bf16x8*)(wb + ((kb      ) ^ cswz));
                bf16x8 azj = *(const bf16x8*)(wb + ((kb + 128) ^ cswz));
                bf16x8 apr = *(const bf16x8*)(wb + ((kb + 256) ^ cswz));
                acc[ct] = mfma16(azi, (h == 0) ? a0 : a1, acc[ct]);
                acc[ct] = mfma16(azj, (h == 0) ? a2 : a3, acc[ct]);
                acc[ct] = mfma16(apr, (h == 0) ? a4 : a5, acc[ct]);
            }
        }
        __builtin_amdgcn_s_setprio(0);

        // ---- epilogue: relu, pack 4xbf16, one ds_write_b64 per ct ----
#pragma unroll
        for (int ct = 0; ct < 4; ++ct) {
            bf16x4 p;
#pragma unroll
            for (int q = 0; q < 4; ++q)
                p[q] = (__bf16)fmaxf(acc[ct][q], 0.f);
            const int wo = (x * 128 + ct * 32 + g * 8) ^ ((x & 7) << 4);
            *(bf16x4*)((char*)h1w + wo) = p;
        }

        // ---- layer 2 (transposed): o[ct][q] = out[e=x][s=ct*16+g*4+q], init = b2 ----
        f32x4 o[4];
#pragma unroll
        for (int ct = 0; ct < 4; ++ct)
            o[ct] = *(const f32x4*)(b2s + ct * 16 + g * 4);

        __builtin_amdgcn_s_setprio(1);
#pragma unroll
        for (int kk = 0; kk < 2; ++kk) {
            const int aoff = (x * 128 + kk * 64 + g * 16) ^ ((x & 7) << 4);
            const bf16x8 h1f = *(const bf16x8*)((const char*)h1w + aoff);
#pragma unroll
            for (int ct = 0; ct < 4; ++ct) {
                const int cols = ct * 16 + x;
                const bf16x8 w2f = *(const bf16x8*)((const char*)w2s + cols * 128
                                                    + ((kk * 64 + g * 16) ^ ((cols & 7) << 4)));
                o[ct] = mfma16(w2f, h1f, o[ct]);
            }
        }
        __builtin_amdgcn_s_setprio(0);

        // ---- store: 4x global_store_dwordx4 ----
        float* orow = out + ((size_t)(m0 + (st * 8 + wave) * 16 + x)) * 64;
#pragma unroll
        for (int ct = 0; ct < 4; ++ct)
            *(f32x4*)(orow + ct * 16 + g * 4) = o[ct];
    }
}

extern "C" void kernel_launch(void* const* d_in, const int* in_sizes, int n_in,
                              void* d_out, int out_size, void* d_ws, size_t ws_size,
                              hipStream_t stream) {
    const float* z     = (const float*)d_in[0];
    const int*   pairs = (const int*)  d_in[1];
    const float* W1    = (const float*)d_in[2];
    const float* b1    = (const float*)d_in[3];
    const float* W2    = (const float*)d_in[4];
    const float* b2    = (const float*)d_in[5];
    float* out = (float*)d_out;

    const int total_rows = 4 * E_TOT;                 // 524288
    dim3 grid(total_rows / ROWS_PER_BLOCK);           // 1024
    PairRelationEncoder_62775241998442_kernel<<<grid, 512, 0, stream>>>(
        z, pairs, W1, b1, W2, b2, out);
}

// Round 5
// 53.724 us; speedup vs baseline: 1.6118x; 1.0972x over previous
//
#include <hip/hip_runtime.h>
#include <hip/hip_bf16.h>
#include <stdint.h>

// PairRelationEncoder: out[b,e,s] = b2[s] + sum_r W2[s,r]*relu(b1[r] + sum_f W1[r,f]*pair[b,e,f])
// pair = [zi, zj, zi-zj, zi*zj] folded to [zi, zj, zi*zj]: Wzi=W1a+W1c, Wzj=W1b-W1c, Wpr=W1d.
// B=4 N=4096 D=64 E=131072 R=64. Out f32 (4,131072,64).
//
// R5: z pre-cast to bf16 in d_ws by a prologue kernel -> gather loads ARE the MFMA fragments
// (4x16B loads/body, 16 regs vs 64, no pack VALU). Slim body + launch_bounds(512,6) targets
// 3 blocks/CU = 24 waves (75% occupancy). Transposed dataflow + LDS weights kept from R4.

typedef __attribute__((ext_vector_type(8))) __bf16 bf16x8;
typedef __attribute__((ext_vector_type(4))) __bf16 bf16x4;
typedef __attribute__((ext_vector_type(4))) float  f32x4;

#define E_TOT 131072
#define N_TOK 4096
#define ROWS_PER_BLOCK 512
#define NSUB 4   // per wave: 4 subtiles x 16 pairs (8 waves -> 512 rows/block)
#define Z_ELEMS (4 * N_TOK * 64)   // 1048576

// ---- prologue: f32 z -> bf16 z in workspace ----
__global__ __launch_bounds__(256) void zcast_kernel(const float* __restrict__ z,
                                                    __bf16* __restrict__ zb)
{
    const int t = blockIdx.x * 256 + threadIdx.x;   // 131072 threads, 8 elems each
    const float4 a = ((const float4*)z)[2 * t];
    const float4 b = ((const float4*)z)[2 * t + 1];
    bf16x8 r;
    r[0] = (__bf16)a.x; r[1] = (__bf16)a.y; r[2] = (__bf16)a.z; r[3] = (__bf16)a.w;
    r[4] = (__bf16)b.x; r[5] = (__bf16)b.y; r[6] = (__bf16)b.z; r[7] = (__bf16)b.w;
    ((bf16x8*)zb)[t] = r;
}

__device__ __forceinline__ f32x4 mfma16(bf16x8 a, bf16x8 b, f32x4 c) {
    return __builtin_amdgcn_mfma_f32_16x16x32_bf16(a, b, c, 0, 0, 0);
}

__device__ __forceinline__ bf16x8 pk8(float4 a, float4 b) {
    bf16x8 r;
    r[0] = (__bf16)a.x; r[1] = (__bf16)a.y; r[2] = (__bf16)a.z; r[3] = (__bf16)a.w;
    r[4] = (__bf16)b.x; r[5] = (__bf16)b.y; r[6] = (__bf16)b.z; r[7] = (__bf16)b.w;
    return r;
}
__device__ __forceinline__ float4 f4add(float4 a, float4 b){ return make_float4(a.x+b.x, a.y+b.y, a.z+b.z, a.w+b.w); }
__device__ __forceinline__ float4 f4sub(float4 a, float4 b){ return make_float4(a.x-b.x, a.y-b.y, a.z-b.z, a.w-b.w); }

__device__ __forceinline__ bf16x8 bmul(bf16x8 a, bf16x8 b) {
    bf16x8 r;
#pragma unroll
    for (int t = 0; t < 8; ++t)
        r[t] = (__bf16)((float)a[t] * (float)b[t]);
    return r;
}

__global__ __launch_bounds__(512, 6) void PairRelationEncoder_62775241998442_kernel(
    const __bf16* __restrict__ zw, const int* __restrict__ pairs,
    const float* __restrict__ W1, const float* __restrict__ b1,
    const float* __restrict__ W2, const float* __restrict__ b2,
    float* __restrict__ out)
{
    const int tid  = threadIdx.x;
    const int wave = tid >> 6;
    const int lane = tid & 63;
    const int x = lane & 15;   // e-index within subtile (B-col / C-col)
    const int g = lane >> 4;   // k-group

    // bijective XCD-chunked swizzle (1024 blocks, 8 XCDs)
    const int bid = (int)(blockIdx.x & 7) * 128 + ((int)blockIdx.x >> 3);
    const int m0 = bid * ROWS_PER_BLOCK;
    const int b  = m0 >> 17;
    const int e0 = m0 & (E_TOT - 1);
    const __bf16* zb = zw + ((size_t)b * N_TOK * 64);

    // hoisted pairs
    int2 ijv[NSUB];
#pragma unroll
    for (int st = 0; st < NSUB; ++st)
        ijv[st] = *(const int2*)(pairs + 2 * (size_t)(e0 + (st * 8 + wave) * 16 + x));

    // LDS: W1f bf16 [r(64)][k(192)] swz, W2 bf16 [s(64)][r(64)] swz, per-wave h1^T, biases f32.
    // 24576 + 8192 + 16384 + 512 = 49664 B -> 3 blocks/CU.
    __shared__ __bf16 w1s[64 * 192];
    __shared__ __bf16 w2s[64 * 64];
    __shared__ __bf16 h1s[8][1024];
    __shared__ float  b1s[64];
    __shared__ float  b2s[64];
    __bf16* h1w = h1s[wave];

    // ---- one-time weight staging: 4 parts x 128 threads ----
    {
        const int part = tid >> 7;            // 0:zi 1:zj 2:pr 3:W2
        const int scol = tid & 63;
        const int c8b  = ((tid >> 6) & 1) * 4;
        const int cswz = (scol & 7) << 4;
        if (part < 3) {
            const float* wr = W1 + (size_t)scol * 256;
            char* dst = (char*)w1s + scol * 384;
#pragma unroll
            for (int c = 0; c < 4; ++c) {
                const int c8 = c8b + c;
                float4 p0, p1;
                if (part == 0) {
                    float4 a0 = *(const float4*)(wr + c8*8);
                    float4 a1 = *(const float4*)(wr + c8*8 + 4);
                    float4 c0 = *(const float4*)(wr + 128 + c8*8);
                    float4 c1 = *(const float4*)(wr + 128 + c8*8 + 4);
                    p0 = f4add(a0, c0); p1 = f4add(a1, c1);
                } else if (part == 1) {
                    float4 a0 = *(const float4*)(wr + 64 + c8*8);
                    float4 a1 = *(const float4*)(wr + 64 + c8*8 + 4);
                    float4 c0 = *(const float4*)(wr + 128 + c8*8);
                    float4 c1 = *(const float4*)(wr + 128 + c8*8 + 4);
                    p0 = f4sub(a0, c0); p1 = f4sub(a1, c1);
                } else {
                    p0 = *(const float4*)(wr + 192 + c8*8);
                    p1 = *(const float4*)(wr + 192 + c8*8 + 4);
                }
                *(bf16x8*)(dst + ((part * 128 + c8 * 16) ^ cswz)) = pk8(p0, p1);
            }
        } else {
            const float* wr = W2 + (size_t)scol * 64;
            char* dst = (char*)w2s + scol * 128;
#pragma unroll
            for (int c = 0; c < 4; ++c) {
                const int c8 = c8b + c;
                float4 p0 = *(const float4*)(wr + c8*8);
                float4 p1 = *(const float4*)(wr + c8*8 + 4);
                *(bf16x8*)(dst + ((c8 * 16) ^ cswz)) = pk8(p0, p1);
            }
        }
        if (tid < 16)            ((float4*)b1s)[tid]      = ((const float4*)b1)[tid];
        else if (tid < 32)       ((float4*)b2s)[tid - 16] = ((const float4*)b2)[tid - 16];
    }

    __syncthreads();

#pragma unroll
    for (int st = 0; st < NSUB; ++st) {
        // ---- gather: 4x 16B loads ARE the zi/zj fragments; product in bf16 ----
        const __bf16* zri = zb + (size_t)ijv[st].x * 64;
        const __bf16* zrj = zb + (size_t)ijv[st].y * 64;
        bf16x8 a0 = *(const bf16x8*)(zri + g * 8);        // zi, d = g*8..+8   (h=0)
        bf16x8 a1 = *(const bf16x8*)(zri + 32 + g * 8);   // zi, h=1
        bf16x8 a2 = *(const bf16x8*)(zrj + g * 8);        // zj, h=0
        bf16x8 a3 = *(const bf16x8*)(zrj + 32 + g * 8);   // zj, h=1
        bf16x8 a4 = bmul(a0, a2);                          // zi*zj, h=0
        bf16x8 a5 = bmul(a1, a3);                          // zi*zj, h=1

        // ---- layer 1 (transposed): acc[ct][q] = h1[r=ct*16+g*4+q][e=x], init = b1 ----
        f32x4 acc[4];
#pragma unroll
        for (int ct = 0; ct < 4; ++ct)
            acc[ct] = *(const f32x4*)(b1s + ct * 16 + g * 4);

#pragma unroll
        for (int h = 0; h < 2; ++h) {
#pragma unroll
            for (int ct = 0; ct < 4; ++ct) {
                const int colr = ct * 16 + x;
                const int cswz = (colr & 7) << 4;
                const char* wb = (const char*)w1s + colr * 384;
                const int kb = h * 64 + g * 16;
                bf16x8 azi = *(const bf16x8*)(wb + ((kb      ) ^ cswz));
                bf16x8 azj = *(const bf16x8*)(wb + ((kb + 128) ^ cswz));
                bf16x8 apr = *(const bf16x8*)(wb + ((kb + 256) ^ cswz));
                acc[ct] = mfma16(azi, (h == 0) ? a0 : a1, acc[ct]);
                acc[ct] = mfma16(azj, (h == 0) ? a2 : a3, acc[ct]);
                acc[ct] = mfma16(apr, (h == 0) ? a4 : a5, acc[ct]);
            }
        }

        // ---- epilogue: relu, pack 4xbf16, one ds_write_b64 per ct ----
#pragma unroll
        for (int ct = 0; ct < 4; ++ct) {
            bf16x4 p;
#pragma unroll
            for (int q = 0; q < 4; ++q)
                p[q] = (__bf16)fmaxf(acc[ct][q], 0.f);
            const int wo = (x * 128 + ct * 32 + g * 8) ^ ((x & 7) << 4);
            *(bf16x4*)((char*)h1w + wo) = p;
        }

        // ---- layer 2 (transposed): o[ct][q] = out[e=x][s=ct*16+g*4+q], init = b2 ----
        f32x4 o[4];
#pragma unroll
        for (int ct = 0; ct < 4; ++ct)
            o[ct] = *(const f32x4*)(b2s + ct * 16 + g * 4);

#pragma unroll
        for (int kk = 0; kk < 2; ++kk) {
            const int aoff = (x * 128 + kk * 64 + g * 16) ^ ((x & 7) << 4);
            const bf16x8 h1f = *(const bf16x8*)((const char*)h1w + aoff);
#pragma unroll
            for (int ct = 0; ct < 4; ++ct) {
                const int cols = ct * 16 + x;
                const bf16x8 w2f = *(const bf16x8*)((const char*)w2s + cols * 128
                                                    + ((kk * 64 + g * 16) ^ ((cols & 7) << 4)));
                o[ct] = mfma16(w2f, h1f, o[ct]);
            }
        }

        // ---- store: 4x global_store_dwordx4 ----
        float* orow = out + ((size_t)(m0 + (st * 8 + wave) * 16 + x)) * 64;
#pragma unroll
        for (int ct = 0; ct < 4; ++ct)
            *(f32x4*)(orow + ct * 16 + g * 4) = o[ct];
    }
}

extern "C" void kernel_launch(void* const* d_in, const int* in_sizes, int n_in,
                              void* d_out, int out_size, void* d_ws, size_t ws_size,
                              hipStream_t stream) {
    const float* z     = (const float*)d_in[0];
    const int*   pairs = (const int*)  d_in[1];
    const float* W1    = (const float*)d_in[2];
    const float* b1    = (const float*)d_in[3];
    const float* W2    = (const float*)d_in[4];
    const float* b2    = (const float*)d_in[5];
    float* out = (float*)d_out;
    __bf16* zw = (__bf16*)d_ws;   // 2 MB bf16 copy of z

    zcast_kernel<<<Z_ELEMS / (256 * 8), 256, 0, stream>>>(z, zw);

    const int total_rows = 4 * E_TOT;                 // 524288
    dim3 grid(total_rows / ROWS_PER_BLOCK);           // 1024
    PairRelationEncoder_62775241998442_kernel<<<grid, 512, 0, stream>>>(
        zw, pairs, W1, b1, W2, b2, out);
}